// Round 1
// baseline (211.786 us; speedup 1.0000x reference)
//
#include <hip/hip_runtime.h>
#include <math.h>

#define ENC 512
#define ATT 256
#define NN 1024
#define PP 1024

// ---------------------------------------------------------------------------
// Kernel 1: u = E @ We^T + be   (z=0)    v = D @ Wt^T + L @ Wl^T + bt + bl (z=1)
// A: (M=1024, K=512) row-major; B: (Nc=256, K=512) row-major; C: (1024, 256)
// 64x64 tile, BK=16, 256 threads, 4x4 per thread, fp32.
// ---------------------------------------------------------------------------
__global__ __launch_bounds__(256) void gemm_bt_uv(
    const float* __restrict__ E,  const float* __restrict__ We, const float* __restrict__ be,
    const float* __restrict__ D,  const float* __restrict__ Wt, const float* __restrict__ bt,
    const float* __restrict__ Lg, const float* __restrict__ Wl, const float* __restrict__ bl,
    float* __restrict__ u, float* __restrict__ v)
{
    const int K = 512, Nc = ATT;
    const float *A0, *B0, *bias0, *A1, *B1, *bias1;
    float* out;
    if (blockIdx.z == 0) { A0=E; B0=We; bias0=be; A1=nullptr; B1=nullptr; bias1=nullptr; out=u; }
    else                 { A0=D; B0=Wt; bias0=bt; A1=Lg;      B1=Wl;      bias1=bl;      out=v; }

    __shared__ float As[16][68];   // [k][m], pad 4 keeps float4 alignment (68*4B % 16 == 0)
    __shared__ float Bs[16][68];   // [k][n]
    const int tid = threadIdx.x;
    const int tx = tid & 15, ty = tid >> 4;      // tx -> n (coalesced C writes), ty -> m
    const int row = tid >> 2, kseg = tid & 3;    // staging: 64 rows x 4 k-segs
    const int m0 = blockIdx.y * 64, n0 = blockIdx.x * 64;

    float acc[4][4];
    #pragma unroll
    for (int i = 0; i < 4; ++i)
        #pragma unroll
        for (int j = 0; j < 4; ++j) acc[i][j] = 0.f;

    for (int pass = 0; pass < 2; ++pass) {
        const float* A = pass ? A1 : A0;
        const float* B = pass ? B1 : B0;
        if (!A) break;
        for (int k0 = 0; k0 < K; k0 += 16) {
            float4 av = *(const float4*)&A[(size_t)(m0 + row) * K + k0 + kseg * 4];
            float4 bv = *(const float4*)&B[(size_t)(n0 + row) * K + k0 + kseg * 4];
            As[kseg*4+0][row] = av.x; As[kseg*4+1][row] = av.y;
            As[kseg*4+2][row] = av.z; As[kseg*4+3][row] = av.w;
            Bs[kseg*4+0][row] = bv.x; Bs[kseg*4+1][row] = bv.y;
            Bs[kseg*4+2][row] = bv.z; Bs[kseg*4+3][row] = bv.w;
            __syncthreads();
            #pragma unroll
            for (int kk = 0; kk < 16; ++kk) {
                float4 a4 = *(const float4*)&As[kk][ty * 4];
                float4 b4 = *(const float4*)&Bs[kk][tx * 4];
                float am[4] = {a4.x, a4.y, a4.z, a4.w};
                float bn[4] = {b4.x, b4.y, b4.z, b4.w};
                #pragma unroll
                for (int i = 0; i < 4; ++i)
                    #pragma unroll
                    for (int j = 0; j < 4; ++j)
                        acc[i][j] = fmaf(am[i], bn[j], acc[i][j]);
            }
            __syncthreads();
        }
    }

    float4 bsv = *(const float4*)&bias0[n0 + tx * 4];
    float bb[4] = {bsv.x, bsv.y, bsv.z, bsv.w};
    if (bias1) {
        float4 b2 = *(const float4*)&bias1[n0 + tx * 4];
        bb[0] += b2.x; bb[1] += b2.y; bb[2] += b2.z; bb[3] += b2.w;
    }
    #pragma unroll
    for (int i = 0; i < 4; ++i) {
        float4 o;
        o.x = acc[i][0] + bb[0]; o.y = acc[i][1] + bb[1];
        o.z = acc[i][2] + bb[2]; o.w = acc[i][3] + bb[3];
        *(float4*)&out[(size_t)(m0 + ty * 4 + i) * Nc + n0 + tx * 4] = o;
    }
}

// ---------------------------------------------------------------------------
// Kernel 2: att[n,p] = sum_a relu(u[p,a] + v[n,a]) * Wf[a]
// (bf[0] is uniform across p -> cancels in softmax; dropped.)
// Block: 256 threads, tile 64p x 64n, thread 4p x 4n, a staged in chunks of 32
// LDS layout transposed to [a][p] / [a][n] so inner loop reads are float4.
// ---------------------------------------------------------------------------
__global__ __launch_bounds__(256) void att_fused(
    const float* __restrict__ u, const float* __restrict__ v,
    const float* __restrict__ Wf, float* __restrict__ att)
{
    __shared__ float us[32][68];
    __shared__ float vs[32][68];
    __shared__ float wfs[ATT];
    const int tid = threadIdx.x;
    wfs[tid] = Wf[tid];                          // 256 threads == ATT
    const int tx = tid & 15, ty = tid >> 4;      // tx -> p, ty -> n
    const int row = tid >> 2, aseg = tid & 3;    // staging: 64 rows x 4 a-segs (8 floats each)
    const int p0 = blockIdx.x * 64, n0 = blockIdx.y * 64;

    float acc[4][4];                             // [j: n][i: p]
    #pragma unroll
    for (int j = 0; j < 4; ++j)
        #pragma unroll
        for (int i = 0; i < 4; ++i) acc[j][i] = 0.f;

    for (int ac = 0; ac < ATT; ac += 32) {
        float4 u0 = *(const float4*)&u[(size_t)(p0 + row) * ATT + ac + aseg * 8];
        float4 u1 = *(const float4*)&u[(size_t)(p0 + row) * ATT + ac + aseg * 8 + 4];
        float4 v0 = *(const float4*)&v[(size_t)(n0 + row) * ATT + ac + aseg * 8];
        float4 v1 = *(const float4*)&v[(size_t)(n0 + row) * ATT + ac + aseg * 8 + 4];
        us[aseg*8+0][row] = u0.x; us[aseg*8+1][row] = u0.y;
        us[aseg*8+2][row] = u0.z; us[aseg*8+3][row] = u0.w;
        us[aseg*8+4][row] = u1.x; us[aseg*8+5][row] = u1.y;
        us[aseg*8+6][row] = u1.z; us[aseg*8+7][row] = u1.w;
        vs[aseg*8+0][row] = v0.x; vs[aseg*8+1][row] = v0.y;
        vs[aseg*8+2][row] = v0.z; vs[aseg*8+3][row] = v0.w;
        vs[aseg*8+4][row] = v1.x; vs[aseg*8+5][row] = v1.y;
        vs[aseg*8+6][row] = v1.z; vs[aseg*8+7][row] = v1.w;
        __syncthreads();
        #pragma unroll
        for (int a = 0; a < 32; ++a) {
            float4 up = *(const float4*)&us[a][tx * 4];
            float4 vn = *(const float4*)&vs[a][ty * 4];
            float w = wfs[ac + a];
            float pu[4] = {up.x, up.y, up.z, up.w};
            float pv[4] = {vn.x, vn.y, vn.z, vn.w};
            #pragma unroll
            for (int j = 0; j < 4; ++j)
                #pragma unroll
                for (int i = 0; i < 4; ++i)
                    acc[j][i] = fmaf(fmaxf(pv[j] + pu[i], 0.f), w, acc[j][i]);
        }
        __syncthreads();
    }

    #pragma unroll
    for (int j = 0; j < 4; ++j) {
        float4 o;
        o.x = acc[j][0]; o.y = acc[j][1]; o.z = acc[j][2]; o.w = acc[j][3];
        *(float4*)&att[(size_t)(n0 + ty * 4 + j) * PP + p0 + tx * 4] = o;
    }
}

// ---------------------------------------------------------------------------
// Kernel 3: in-place row softmax over p. One block per n, 256 threads x 4 elems.
// Safe in place: every thread reads its 4 elements before any thread writes.
// ---------------------------------------------------------------------------
__global__ __launch_bounds__(256) void softmax_rows(float* __restrict__ att)
{
    const int n = blockIdx.x;
    const int tid = threadIdx.x;
    float* rowp = att + (size_t)n * PP;
    float4 x = *(const float4*)&rowp[tid * 4];

    float m = fmaxf(fmaxf(x.x, x.y), fmaxf(x.z, x.w));
    #pragma unroll
    for (int off = 32; off > 0; off >>= 1) m = fmaxf(m, __shfl_xor(m, off));
    __shared__ float redm[4];
    const int wave = tid >> 6, lane = tid & 63;
    if (lane == 0) redm[wave] = m;
    __syncthreads();
    m = fmaxf(fmaxf(redm[0], redm[1]), fmaxf(redm[2], redm[3]));

    float e0 = expf(x.x - m), e1 = expf(x.y - m), e2 = expf(x.z - m), e3 = expf(x.w - m);
    float s = e0 + e1 + e2 + e3;
    #pragma unroll
    for (int off = 32; off > 0; off >>= 1) s += __shfl_xor(s, off);
    __shared__ float reds[4];
    if (lane == 0) reds[wave] = s;
    __syncthreads();
    s = reds[0] + reds[1] + reds[2] + reds[3];
    const float inv = 1.0f / s;

    float4 o;
    o.x = e0 * inv; o.y = e1 * inv; o.z = e2 * inv; o.w = e3 * inv;
    *(float4*)&rowp[tid * 4] = o;
}

// ---------------------------------------------------------------------------
// Kernel 4: awe = alpha @ E.  A: (1024, 1024) row-major; B: (1024, 512) row-major.
// Same 64x64 tiling, B loaded non-transposed.
// ---------------------------------------------------------------------------
__global__ __launch_bounds__(256) void gemm_bn_awe(
    const float* __restrict__ Aalpha, const float* __restrict__ Bmat,
    float* __restrict__ C)
{
    const int K = PP, Nc = ENC;
    __shared__ float As[16][68];
    __shared__ float Bs[16][68];
    const int tid = threadIdx.x;
    const int tx = tid & 15, ty = tid >> 4;
    const int rowA = tid >> 2, ksegA = tid & 3;
    const int rowB = tid >> 4, csegB = tid & 15;   // 16 k-rows x 16 col-segs
    const int m0 = blockIdx.y * 64, n0 = blockIdx.x * 64;

    float acc[4][4];
    #pragma unroll
    for (int i = 0; i < 4; ++i)
        #pragma unroll
        for (int j = 0; j < 4; ++j) acc[i][j] = 0.f;

    for (int k0 = 0; k0 < K; k0 += 16) {
        float4 av = *(const float4*)&Aalpha[(size_t)(m0 + rowA) * K + k0 + ksegA * 4];
        As[ksegA*4+0][rowA] = av.x; As[ksegA*4+1][rowA] = av.y;
        As[ksegA*4+2][rowA] = av.z; As[ksegA*4+3][rowA] = av.w;
        float4 bv = *(const float4*)&Bmat[(size_t)(k0 + rowB) * Nc + n0 + csegB * 4];
        *(float4*)&Bs[rowB][csegB * 4] = bv;
        __syncthreads();
        #pragma unroll
        for (int kk = 0; kk < 16; ++kk) {
            float4 a4 = *(const float4*)&As[kk][ty * 4];
            float4 b4 = *(const float4*)&Bs[kk][tx * 4];
            float am[4] = {a4.x, a4.y, a4.z, a4.w};
            float bn[4] = {b4.x, b4.y, b4.z, b4.w};
            #pragma unroll
            for (int i = 0; i < 4; ++i)
                #pragma unroll
                for (int j = 0; j < 4; ++j)
                    acc[i][j] = fmaf(am[i], bn[j], acc[i][j]);
        }
        __syncthreads();
    }
    #pragma unroll
    for (int i = 0; i < 4; ++i) {
        float4 o;
        o.x = acc[i][0]; o.y = acc[i][1]; o.z = acc[i][2]; o.w = acc[i][3];
        *(float4*)&C[(size_t)(m0 + ty * 4 + i) * Nc + n0 + tx * 4] = o;
    }
}

// ---------------------------------------------------------------------------
extern "C" void kernel_launch(void* const* d_in, const int* in_sizes, int n_in,
                              void* d_out, int out_size, void* d_ws, size_t ws_size,
                              hipStream_t stream)
{
    const float* encoder = (const float*)d_in[0];  // (1, 1024, 512)
    const float* dec     = (const float*)d_in[1];  // (1024, 512)
    const float* lang    = (const float*)d_in[2];  // (1024, 512)
    const float* We      = (const float*)d_in[3];  // (256, 512)
    const float* be      = (const float*)d_in[4];  // (256,)
    const float* Wt      = (const float*)d_in[5];
    const float* bt      = (const float*)d_in[6];
    const float* Wl      = (const float*)d_in[7];
    const float* bl      = (const float*)d_in[8];
    const float* Wf      = (const float*)d_in[9];  // (1, 256)
    // d_in[10] = bf: uniform over p -> cancels in softmax; att itself not an output.

    float* u = (float*)d_ws;                 // 1024*256 floats (1 MB)
    float* v = u + NN * ATT;                 // 1024*256 floats (1 MB)

    float* awe   = (float*)d_out;            // (1024, 512)
    float* alpha = (float*)d_out + NN * ENC; // (1024, 1024); also used as att scratch

    // u / v
    gemm_bt_uv<<<dim3(ATT / 64, NN / 64, 2), 256, 0, stream>>>(
        encoder, We, be, dec, Wt, bt, lang, Wl, bl, u, v);
    // att logits (written into alpha's slot in d_out)
    att_fused<<<dim3(PP / 64, NN / 64), 256, 0, stream>>>(u, v, Wf, alpha);
    // softmax in place -> alpha
    softmax_rows<<<dim3(NN), 256, 0, stream>>>(alpha);
    // awe = alpha @ E
    gemm_bn_awe<<<dim3(ENC / 64, NN / 64), 256, 0, stream>>>(alpha, encoder, awe);
}

// Round 3
// 154.324 us; speedup vs baseline: 1.3723x; 1.3723x over previous
//
#include <hip/hip_runtime.h>
#include <math.h>

#define ENC 512
#define ATT 256
#define NN 1024
#define PP 1024

typedef __attribute__((ext_vector_type(8))) __bf16 bf16x8;
typedef __attribute__((ext_vector_type(4))) float floatx4;

union LdsVec { uint4 u; bf16x8 v; };

__device__ __forceinline__ unsigned short f2bf(float f) {
    union { float f; unsigned u; } x; x.f = f;
    unsigned r = x.u + 0x7fffu + ((x.u >> 16) & 1u);   // round-to-nearest-even
    return (unsigned short)(r >> 16);
}

// LDS tile: [64 rows][32 k] bf16, row stride 64B; 16B chunks XOR-swizzled by
// (row>>1)&3 -> frag reads and staged writes are both <=2-way bank aliased (free).
__device__ __forceinline__ int tile_off(int row, int k) {
    return row * 32 + ((((k >> 3) ^ ((row >> 1) & 3)) & 3) << 3) + (k & 7);
}

// Stage a 64-row x 32-k tile of row-major fp32 (leading dim ld) into bf16 LDS.
// src must already point at element [row0=0][k=0] of the 64-row slab.
__device__ __forceinline__ void stage_bt(unsigned short* dst, const float* __restrict__ src,
                                         int ld, int k0, int tid) {
    const int row = tid >> 2, kseg = tid & 3;          // 8 k-elems per thread
    const float* p = src + (size_t)row * ld + k0 + kseg * 8;
    float4 f0 = *(const float4*)p;
    float4 f1 = *(const float4*)(p + 4);
    unsigned short tmp[8] = {f2bf(f0.x), f2bf(f0.y), f2bf(f0.z), f2bf(f0.w),
                             f2bf(f1.x), f2bf(f1.y), f2bf(f1.z), f2bf(f1.w)};
    *(uint4*)&dst[tile_off(row, kseg * 8)] = *(uint4*)tmp;
}

// ---------------------------------------------------------------------------
// MFMA GEMM C = A@B^T (+bias), A:(M,K) B:(N,K) fp32 row-major, C fp32 (M,N).
// z=0: u = E@We^T + be ; z=1: v = D@Wt^T + L@Wl^T + bt + bl.
// Block 256 thr (4 waves, 2x2 wave grid), tile 64x64, BK=32, 16x16x32 bf16 MFMA.
// ---------------------------------------------------------------------------
__global__ __launch_bounds__(256) void mfma_uv(
    const float* __restrict__ E,  const float* __restrict__ We, const float* __restrict__ be,
    const float* __restrict__ D,  const float* __restrict__ Wt, const float* __restrict__ bt,
    const float* __restrict__ Lg, const float* __restrict__ Wl, const float* __restrict__ bl,
    float* __restrict__ u, float* __restrict__ v)
{
    __shared__ __align__(16) unsigned short As[64 * 32];
    __shared__ __align__(16) unsigned short Bs[64 * 32];
    const int tid = threadIdx.x;
    const int K = 512;

    const float *A0, *B0, *A1, *B1, *bp0, *bp1;
    float* out;
    if (blockIdx.z == 0) { A0 = E; B0 = We; A1 = nullptr; B1 = nullptr; bp0 = be; bp1 = nullptr; out = u; }
    else                 { A0 = D; B0 = Wt; A1 = Lg;      B1 = Wl;      bp0 = bt; bp1 = bl;      out = v; }

    const int m0 = blockIdx.y * 64, n0 = blockIdx.x * 64;
    const int wv = tid >> 6, lm = tid & 15, lq = (tid >> 4) & 3;
    const int mb = (wv & 1) * 32, nb = (wv >> 1) * 32;
    const int a0o = tile_off(mb + lm,      lq * 8);
    const int a1o = tile_off(mb + 16 + lm, lq * 8);
    const int b0o = tile_off(nb + lm,      lq * 8);
    const int b1o = tile_off(nb + 16 + lm, lq * 8);

    floatx4 acc[2][2];
    const floatx4 zero = {0.f, 0.f, 0.f, 0.f};
    acc[0][0] = zero; acc[0][1] = zero; acc[1][0] = zero; acc[1][1] = zero;

    for (int pass = 0; pass < 2; ++pass) {
        const float* A = pass ? A1 : A0;
        const float* B = pass ? B1 : B0;
        if (!A) break;
        const float* Am = A + (size_t)m0 * K;
        const float* Bn = B + (size_t)n0 * K;
        for (int k0 = 0; k0 < K; k0 += 32) {
            __syncthreads();                    // prior frag reads done
            stage_bt(As, Am, K, k0, tid);
            stage_bt(Bs, Bn, K, k0, tid);
            __syncthreads();
            LdsVec fa0, fa1, fb0, fb1;
            fa0.u = *(const uint4*)&As[a0o];
            fa1.u = *(const uint4*)&As[a1o];
            fb0.u = *(const uint4*)&Bs[b0o];
            fb1.u = *(const uint4*)&Bs[b1o];
            acc[0][0] = __builtin_amdgcn_mfma_f32_16x16x32_bf16(fa0.v, fb0.v, acc[0][0], 0, 0, 0);
            acc[0][1] = __builtin_amdgcn_mfma_f32_16x16x32_bf16(fa0.v, fb1.v, acc[0][1], 0, 0, 0);
            acc[1][0] = __builtin_amdgcn_mfma_f32_16x16x32_bf16(fa1.v, fb0.v, acc[1][0], 0, 0, 0);
            acc[1][1] = __builtin_amdgcn_mfma_f32_16x16x32_bf16(fa1.v, fb1.v, acc[1][1], 0, 0, 0);
        }
    }

    #pragma unroll
    for (int s = 0; s < 2; ++s) {
        const int col = n0 + nb + s * 16 + lm;
        const float bsum = bp0[col] + (bp1 ? bp1[col] : 0.f);
        #pragma unroll
        for (int t = 0; t < 2; ++t)
            #pragma unroll
            for (int r = 0; r < 4; ++r)
                out[(size_t)(m0 + mb + t * 16 + lq * 4 + r) * ATT + col] = acc[t][s][r] + bsum;
    }
}

// ---------------------------------------------------------------------------
// MFMA GEMM awe = alpha @ E.  alpha:(1024,1024), E:(1024,512) row-major (k,n)
// -> B staged TRANSPOSED into LDS.  Tile 64x64, BK=32.
// B tile = 64 n-rows x 32 k = 2048 elems -> each of 256 threads stages TWO
// float4s (cols cc and cc+32).  [Round-2 bug: only one -> half tile garbage.]
// ---------------------------------------------------------------------------
__global__ __launch_bounds__(256) void mfma_awe(
    const float* __restrict__ alpha, const float* __restrict__ Emat,
    float* __restrict__ awe)
{
    __shared__ __align__(16) unsigned short As[64 * 32];
    __shared__ __align__(16) unsigned short Bs[64 * 32];
    const int tid = threadIdx.x;
    const int K = PP;
    const int m0 = blockIdx.y * 64, n0 = blockIdx.x * 64;
    const int wv = tid >> 6, lm = tid & 15, lq = (tid >> 4) & 3;
    const int mb = (wv & 1) * 32, nb = (wv >> 1) * 32;
    const int a0o = tile_off(mb + lm,      lq * 8);
    const int a1o = tile_off(mb + 16 + lm, lq * 8);
    const int b0o = tile_off(nb + lm,      lq * 8);
    const int b1o = tile_off(nb + 16 + lm, lq * 8);
    const int kr = tid >> 3, cc = (tid & 7) * 4;       // B-transpose staging coords

    const float* Am = alpha + (size_t)m0 * K;

    floatx4 acc[2][2];
    const floatx4 zero = {0.f, 0.f, 0.f, 0.f};
    acc[0][0] = zero; acc[0][1] = zero; acc[1][0] = zero; acc[1][1] = zero;

    for (int k0 = 0; k0 < K; k0 += 32) {
        __syncthreads();
        stage_bt(As, Am, K, k0, tid);
        {   // E[k0+kr][n0 + cc(+32) ..] -> Bs[n][k] transposed; both halves!
            const float* ep = &Emat[(size_t)(k0 + kr) * ENC + n0];
            float4 f = *(const float4*)(ep + cc);
            float4 g = *(const float4*)(ep + cc + 32);
            Bs[tile_off(cc + 0, kr)] = f2bf(f.x);
            Bs[tile_off(cc + 1, kr)] = f2bf(f.y);
            Bs[tile_off(cc + 2, kr)] = f2bf(f.z);
            Bs[tile_off(cc + 3, kr)] = f2bf(f.w);
            Bs[tile_off(cc + 32, kr)] = f2bf(g.x);
            Bs[tile_off(cc + 33, kr)] = f2bf(g.y);
            Bs[tile_off(cc + 34, kr)] = f2bf(g.z);
            Bs[tile_off(cc + 35, kr)] = f2bf(g.w);
        }
        __syncthreads();
        LdsVec fa0, fa1, fb0, fb1;
        fa0.u = *(const uint4*)&As[a0o];
        fa1.u = *(const uint4*)&As[a1o];
        fb0.u = *(const uint4*)&Bs[b0o];
        fb1.u = *(const uint4*)&Bs[b1o];
        acc[0][0] = __builtin_amdgcn_mfma_f32_16x16x32_bf16(fa0.v, fb0.v, acc[0][0], 0, 0, 0);
        acc[0][1] = __builtin_amdgcn_mfma_f32_16x16x32_bf16(fa0.v, fb1.v, acc[0][1], 0, 0, 0);
        acc[1][0] = __builtin_amdgcn_mfma_f32_16x16x32_bf16(fa1.v, fb0.v, acc[1][0], 0, 0, 0);
        acc[1][1] = __builtin_amdgcn_mfma_f32_16x16x32_bf16(fa1.v, fb1.v, acc[1][1], 0, 0, 0);
    }

    #pragma unroll
    for (int s = 0; s < 2; ++s) {
        const int col = n0 + nb + s * 16 + lm;
        #pragma unroll
        for (int t = 0; t < 2; ++t)
            #pragma unroll
            for (int r = 0; r < 4; ++r)
                awe[(size_t)(m0 + mb + t * 16 + lq * 4 + r) * ENC + col] = acc[t][s][r];
    }
}

// ---------------------------------------------------------------------------
// att[n,p] = sum_a relu(u[p,a] + v[n,a]) * Wf[a]   (bf cancels in softmax)
// Tile 64p x 32n, 256 thr, thread 4p x 2n -> grid 16x32 = 512 blocks
// (2 blocks/CU, 8 waves/CU).  fp32 VALU; LDS transposed to [a][p]/[a][n].
// ---------------------------------------------------------------------------
__global__ __launch_bounds__(256) void att_fused(
    const float* __restrict__ u, const float* __restrict__ v,
    const float* __restrict__ Wf, float* __restrict__ att)
{
    __shared__ float us[32][68];
    __shared__ float vs[32][36];
    __shared__ float wfs[ATT];
    const int tid = threadIdx.x;
    wfs[tid] = Wf[tid];
    const int p0 = blockIdx.x * 64, n0 = blockIdx.y * 32;
    const int urow = tid & 63, uas = tid >> 6;   // u stage: 64 p-rows x 8 a
    const int vrow = tid & 31, vas = tid >> 5;   // v stage: 32 n-rows x 4 a
    const int tx = tid & 15, ty = tid >> 4;      // compute: p = tx*4.., n = ty*2..

    float acc[2][4];
    #pragma unroll
    for (int j = 0; j < 2; ++j)
        #pragma unroll
        for (int i = 0; i < 4; ++i) acc[j][i] = 0.f;

    for (int ac = 0; ac < ATT; ac += 32) {
        __syncthreads();
        {
            const float* up = &u[(size_t)(p0 + urow) * ATT + ac + uas * 8];
            float4 f0 = *(const float4*)up;
            float4 f1 = *(const float4*)(up + 4);
            us[uas*8+0][urow] = f0.x; us[uas*8+1][urow] = f0.y;
            us[uas*8+2][urow] = f0.z; us[uas*8+3][urow] = f0.w;
            us[uas*8+4][urow] = f1.x; us[uas*8+5][urow] = f1.y;
            us[uas*8+6][urow] = f1.z; us[uas*8+7][urow] = f1.w;
            const float* vp = &v[(size_t)(n0 + vrow) * ATT + ac + vas * 4];
            float4 g = *(const float4*)vp;
            vs[vas*4+0][vrow] = g.x; vs[vas*4+1][vrow] = g.y;
            vs[vas*4+2][vrow] = g.z; vs[vas*4+3][vrow] = g.w;
        }
        __syncthreads();
        #pragma unroll
        for (int a = 0; a < 32; ++a) {
            float4 up4 = *(const float4*)&us[a][tx * 4];
            float2 vn2 = *(const float2*)&vs[a][ty * 2];
            const float w = wfs[ac + a];
            acc[0][0] = fmaf(fmaxf(vn2.x + up4.x, 0.f), w, acc[0][0]);
            acc[0][1] = fmaf(fmaxf(vn2.x + up4.y, 0.f), w, acc[0][1]);
            acc[0][2] = fmaf(fmaxf(vn2.x + up4.z, 0.f), w, acc[0][2]);
            acc[0][3] = fmaf(fmaxf(vn2.x + up4.w, 0.f), w, acc[0][3]);
            acc[1][0] = fmaf(fmaxf(vn2.y + up4.x, 0.f), w, acc[1][0]);
            acc[1][1] = fmaf(fmaxf(vn2.y + up4.y, 0.f), w, acc[1][1]);
            acc[1][2] = fmaf(fmaxf(vn2.y + up4.z, 0.f), w, acc[1][2]);
            acc[1][3] = fmaf(fmaxf(vn2.y + up4.w, 0.f), w, acc[1][3]);
        }
    }

    #pragma unroll
    for (int j = 0; j < 2; ++j) {
        float4 o;
        o.x = acc[j][0]; o.y = acc[j][1]; o.z = acc[j][2]; o.w = acc[j][3];
        *(float4*)&att[(size_t)(n0 + ty * 2 + j) * PP + p0 + tx * 4] = o;
    }
}

// ---------------------------------------------------------------------------
// Row softmax, wave-per-row (no barriers).  Block 256 thr = 4 rows; grid 256.
// ---------------------------------------------------------------------------
__global__ __launch_bounds__(256) void softmax_rows(float* __restrict__ att)
{
    const int wv = threadIdx.x >> 6, lane = threadIdx.x & 63;
    const int n = blockIdx.x * 4 + wv;
    float* row = att + (size_t)n * PP;

    float4 x[4];
    #pragma unroll
    for (int i = 0; i < 4; ++i) x[i] = *(const float4*)&row[i * 256 + lane * 4];

    float m = -1e30f;
    #pragma unroll
    for (int i = 0; i < 4; ++i)
        m = fmaxf(m, fmaxf(fmaxf(x[i].x, x[i].y), fmaxf(x[i].z, x[i].w)));
    #pragma unroll
    for (int off = 32; off > 0; off >>= 1) m = fmaxf(m, __shfl_xor(m, off, 64));

    float s = 0.f;
    #pragma unroll
    for (int i = 0; i < 4; ++i) {
        x[i].x = __expf(x[i].x - m); x[i].y = __expf(x[i].y - m);
        x[i].z = __expf(x[i].z - m); x[i].w = __expf(x[i].w - m);
        s += x[i].x + x[i].y + x[i].z + x[i].w;
    }
    #pragma unroll
    for (int off = 32; off > 0; off >>= 1) s += __shfl_xor(s, off, 64);
    const float inv = 1.0f / s;

    #pragma unroll
    for (int i = 0; i < 4; ++i) {
        x[i].x *= inv; x[i].y *= inv; x[i].z *= inv; x[i].w *= inv;
        *(float4*)&row[i * 256 + lane * 4] = x[i];
    }
}

// ---------------------------------------------------------------------------
extern "C" void kernel_launch(void* const* d_in, const int* in_sizes, int n_in,
                              void* d_out, int out_size, void* d_ws, size_t ws_size,
                              hipStream_t stream)
{
    const float* encoder = (const float*)d_in[0];
    const float* dec     = (const float*)d_in[1];
    const float* lang    = (const float*)d_in[2];
    const float* We      = (const float*)d_in[3];
    const float* be      = (const float*)d_in[4];
    const float* Wt      = (const float*)d_in[5];
    const float* bt      = (const float*)d_in[6];
    const float* Wl      = (const float*)d_in[7];
    const float* bl      = (const float*)d_in[8];
    const float* Wf      = (const float*)d_in[9];
    // d_in[10] = bf: uniform over p -> cancels in softmax.

    float* u = (float*)d_ws;
    float* v = u + NN * ATT;

    float* awe   = (float*)d_out;
    float* alpha = (float*)d_out + NN * ENC;

    mfma_uv<<<dim3(ATT / 64, NN / 64, 2), 256, 0, stream>>>(
        encoder, We, be, dec, Wt, bt, lang, Wl, bl, u, v);
    att_fused<<<dim3(PP / 64, NN / 32), 256, 0, stream>>>(u, v, Wf, alpha);
    softmax_rows<<<dim3(NN / 4), 256, 0, stream>>>(alpha);
    mfma_awe<<<dim3(ENC / 64, NN / 64), 256, 0, stream>>>(alpha, encoder, awe);
}

// Round 4
// 139.124 us; speedup vs baseline: 1.5223x; 1.1093x over previous
//
#include <hip/hip_runtime.h>
#include <math.h>

#define ENC 512
#define ATT 256
#define NN 1024
#define PP 1024

typedef __attribute__((ext_vector_type(8))) __bf16 bf16x8;
typedef __attribute__((ext_vector_type(4))) float floatx4;
typedef __attribute__((ext_vector_type(2))) float floatx2;

union LdsVec { uint4 u; bf16x8 v; };

__device__ __forceinline__ unsigned short f2bf(float f) {
    union { float f; unsigned u; } x; x.f = f;
    unsigned r = x.u + 0x7fffu + ((x.u >> 16) & 1u);   // round-to-nearest-even
    return (unsigned short)(r >> 16);
}

// LDS tile: [64 rows][32 k] bf16, row stride 64B; 16B chunks XOR-swizzled by
// (row>>1)&3 -> frag reads and staged writes are both <=2-way bank aliased.
__device__ __forceinline__ int tile_off(int row, int k) {
    return row * 32 + ((((k >> 3) ^ ((row >> 1) & 3)) & 3) << 3) + (k & 7);
}

// Convert 2 float4s (8 consecutive k) to bf16 and write one 16B LDS chunk.
__device__ __forceinline__ void cvt_store(unsigned short* dst, int off, float4 f0, float4 f1) {
    unsigned short tmp[8] = {f2bf(f0.x), f2bf(f0.y), f2bf(f0.z), f2bf(f0.w),
                             f2bf(f1.x), f2bf(f1.y), f2bf(f1.z), f2bf(f1.w)};
    *(uint4*)&dst[off] = *(uint4*)tmp;
}

// ---------------------------------------------------------------------------
// MFMA GEMM C = A@B^T + bias.  A:(1024,512) B:(256,512) fp32 row-major.
// z=0: u = E@We^T+be ; z=1: v1 = D@Wt^T+bt ; z=2: v2 = L@Wl^T+bl.
// 64x64 tile, BK=32, 4 waves (2x2), DOUBLE-BUFFERED LDS + register prefetch.
// Grid 4x16x3 = 192 balanced blocks (16 K-steps each).
// ---------------------------------------------------------------------------
__global__ __launch_bounds__(256) void mfma_uv(
    const float* __restrict__ E,  const float* __restrict__ We, const float* __restrict__ be,
    const float* __restrict__ D,  const float* __restrict__ Wt, const float* __restrict__ bt,
    const float* __restrict__ Lg, const float* __restrict__ Wl, const float* __restrict__ bl,
    float* __restrict__ u, float* __restrict__ v1, float* __restrict__ v2)
{
    __shared__ __align__(16) unsigned short As[2][64 * 32];
    __shared__ __align__(16) unsigned short Bs[2][64 * 32];
    const int tid = threadIdx.x;
    const int K = 512;

    const float *A, *B, *bias; float* out;
    if      (blockIdx.z == 0) { A = E;  B = We; bias = be; out = u;  }
    else if (blockIdx.z == 1) { A = D;  B = Wt; bias = bt; out = v1; }
    else                      { A = Lg; B = Wl; bias = bl; out = v2; }

    const int m0 = blockIdx.y * 64, n0 = blockIdx.x * 64;
    const int wv = tid >> 6, lm = tid & 15, lq = (tid >> 4) & 3;
    const int mb = (wv & 1) * 32, nb = (wv >> 1) * 32;
    const int a0o = tile_off(mb + lm,      lq * 8);
    const int a1o = tile_off(mb + 16 + lm, lq * 8);
    const int b0o = tile_off(nb + lm,      lq * 8);
    const int b1o = tile_off(nb + 16 + lm, lq * 8);

    const int row = tid >> 2, kseg = tid & 3;           // staging coords
    const int soff = tile_off(row, kseg * 8);
    const float* Ap = A + (size_t)(m0 + row) * K + kseg * 8;
    const float* Bp = B + (size_t)(n0 + row) * K + kseg * 8;

    floatx4 acc[2][2];
    const floatx4 zero = {0.f, 0.f, 0.f, 0.f};
    acc[0][0] = zero; acc[0][1] = zero; acc[1][0] = zero; acc[1][1] = zero;

    // prefetch k=0
    float4 pa0 = *(const float4*)(Ap),     pa1 = *(const float4*)(Ap + 4);
    float4 pb0 = *(const float4*)(Bp),     pb1 = *(const float4*)(Bp + 4);

    for (int k0 = 0; k0 < K; k0 += 32) {
        const int buf = (k0 >> 5) & 1;
        cvt_store(As[buf], soff, pa0, pa1);
        cvt_store(Bs[buf], soff, pb0, pb1);
        __syncthreads();
        if (k0 + 32 < K) {                              // prefetch next chunk
            pa0 = *(const float4*)(Ap + k0 + 32); pa1 = *(const float4*)(Ap + k0 + 36);
            pb0 = *(const float4*)(Bp + k0 + 32); pb1 = *(const float4*)(Bp + k0 + 36);
        }
        LdsVec fa0, fa1, fb0, fb1;
        fa0.u = *(const uint4*)&As[buf][a0o];
        fa1.u = *(const uint4*)&As[buf][a1o];
        fb0.u = *(const uint4*)&Bs[buf][b0o];
        fb1.u = *(const uint4*)&Bs[buf][b1o];
        acc[0][0] = __builtin_amdgcn_mfma_f32_16x16x32_bf16(fa0.v, fb0.v, acc[0][0], 0, 0, 0);
        acc[0][1] = __builtin_amdgcn_mfma_f32_16x16x32_bf16(fa0.v, fb1.v, acc[0][1], 0, 0, 0);
        acc[1][0] = __builtin_amdgcn_mfma_f32_16x16x32_bf16(fa1.v, fb0.v, acc[1][0], 0, 0, 0);
        acc[1][1] = __builtin_amdgcn_mfma_f32_16x16x32_bf16(fa1.v, fb1.v, acc[1][1], 0, 0, 0);
        // next iteration writes the OTHER buffer; reads above finished before
        // its __syncthreads -> single barrier per step is sufficient.
    }

    #pragma unroll
    for (int s = 0; s < 2; ++s) {
        const int col = n0 + nb + s * 16 + lm;
        const float bsum = bias[col];
        #pragma unroll
        for (int t = 0; t < 2; ++t)
            #pragma unroll
            for (int r = 0; r < 4; ++r)
                out[(size_t)(m0 + mb + t * 16 + lq * 4 + r) * ATT + col] = acc[t][s][r] + bsum;
    }
}

// ---------------------------------------------------------------------------
// MFMA GEMM awe = alpha @ E.  alpha:(1024,1024), E:(1024,512) (k,n) row-major
// -> B staged TRANSPOSED.  64x64 tile, BK=32, double-buffered, 128 blocks.
// ---------------------------------------------------------------------------
__global__ __launch_bounds__(256) void mfma_awe(
    const float* __restrict__ alpha, const float* __restrict__ Emat,
    float* __restrict__ awe)
{
    __shared__ __align__(16) unsigned short As[2][64 * 32];
    __shared__ __align__(16) unsigned short Bs[2][64 * 32];
    const int tid = threadIdx.x;
    const int K = PP;
    const int m0 = blockIdx.y * 64, n0 = blockIdx.x * 64;
    const int wv = tid >> 6, lm = tid & 15, lq = (tid >> 4) & 3;
    const int mb = (wv & 1) * 32, nb = (wv >> 1) * 32;
    const int a0o = tile_off(mb + lm,      lq * 8);
    const int a1o = tile_off(mb + 16 + lm, lq * 8);
    const int b0o = tile_off(nb + lm,      lq * 8);
    const int b1o = tile_off(nb + 16 + lm, lq * 8);

    const int row = tid >> 2, kseg = tid & 3;           // A staging
    const int soff = tile_off(row, kseg * 8);
    const float* Ap = alpha + (size_t)(m0 + row) * K + kseg * 8;
    const int kr = tid >> 3, cc = (tid & 7) * 4;        // B-transpose staging
    const float* Ep = Emat + (size_t)kr * ENC + n0;

    floatx4 acc[2][2];
    const floatx4 zero = {0.f, 0.f, 0.f, 0.f};
    acc[0][0] = zero; acc[0][1] = zero; acc[1][0] = zero; acc[1][1] = zero;

    float4 pa0 = *(const float4*)(Ap),  pa1 = *(const float4*)(Ap + 4);
    float4 pe0 = *(const float4*)(Ep + cc);
    float4 pe1 = *(const float4*)(Ep + cc + 32);

    for (int k0 = 0; k0 < K; k0 += 32) {
        const int buf = (k0 >> 5) & 1;
        cvt_store(As[buf], soff, pa0, pa1);
        unsigned short* Bb = Bs[buf];
        Bb[tile_off(cc + 0, kr)] = f2bf(pe0.x);
        Bb[tile_off(cc + 1, kr)] = f2bf(pe0.y);
        Bb[tile_off(cc + 2, kr)] = f2bf(pe0.z);
        Bb[tile_off(cc + 3, kr)] = f2bf(pe0.w);
        Bb[tile_off(cc + 32, kr)] = f2bf(pe1.x);
        Bb[tile_off(cc + 33, kr)] = f2bf(pe1.y);
        Bb[tile_off(cc + 34, kr)] = f2bf(pe1.z);
        Bb[tile_off(cc + 35, kr)] = f2bf(pe1.w);
        __syncthreads();
        if (k0 + 32 < K) {
            pa0 = *(const float4*)(Ap + k0 + 32); pa1 = *(const float4*)(Ap + k0 + 36);
            const float* ep = Ep + (size_t)(k0 + 32) * ENC;
            pe0 = *(const float4*)(ep + cc);
            pe1 = *(const float4*)(ep + cc + 32);
        }
        LdsVec fa0, fa1, fb0, fb1;
        fa0.u = *(const uint4*)&As[buf][a0o];
        fa1.u = *(const uint4*)&As[buf][a1o];
        fb0.u = *(const uint4*)&Bs[buf][b0o];
        fb1.u = *(const uint4*)&Bs[buf][b1o];
        acc[0][0] = __builtin_amdgcn_mfma_f32_16x16x32_bf16(fa0.v, fb0.v, acc[0][0], 0, 0, 0);
        acc[0][1] = __builtin_amdgcn_mfma_f32_16x16x32_bf16(fa0.v, fb1.v, acc[0][1], 0, 0, 0);
        acc[1][0] = __builtin_amdgcn_mfma_f32_16x16x32_bf16(fa1.v, fb0.v, acc[1][0], 0, 0, 0);
        acc[1][1] = __builtin_amdgcn_mfma_f32_16x16x32_bf16(fa1.v, fb1.v, acc[1][1], 0, 0, 0);
    }

    #pragma unroll
    for (int s = 0; s < 2; ++s) {
        const int col = n0 + nb + s * 16 + lm;
        #pragma unroll
        for (int t = 0; t < 2; ++t)
            #pragma unroll
            for (int r = 0; r < 4; ++r)
                awe[(size_t)(m0 + mb + t * 16 + lq * 4 + r) * ENC + col] = acc[t][s][r];
    }
}

// ---------------------------------------------------------------------------
// att[n,p] = sum_a relu(u[p,a] + v1[n,a] + v2[n,a]) * Wf[a]  (bf cancels)
// Tile 64p x 32n, 512 blocks.  Inner loop in float2 so compiler emits
// v_pk_add_f32 / v_pk_fma_f32 (16 VALU issues per a-step vs 24 scalar).
// ---------------------------------------------------------------------------
__global__ __launch_bounds__(256) void att_fused(
    const float* __restrict__ u, const float* __restrict__ v1,
    const float* __restrict__ v2,
    const float* __restrict__ Wf, float* __restrict__ att)
{
    __shared__ float us[32][68];
    __shared__ float vs[32][36];
    __shared__ float wfs[ATT];
    const int tid = threadIdx.x;
    wfs[tid] = Wf[tid];
    const int p0 = blockIdx.x * 64, n0 = blockIdx.y * 32;
    const int urow = tid & 63, uas = tid >> 6;   // u stage: 64 p-rows x 8 a
    const int vrow = tid & 31, vas = tid >> 5;   // v stage: 32 n-rows x 4 a
    const int tx = tid & 15, ty = tid >> 4;      // compute: p = tx*4.., n = ty*2..

    floatx2 acc[2][2];                           // [n j][p pair]
    const floatx2 z2 = {0.f, 0.f};
    acc[0][0] = z2; acc[0][1] = z2; acc[1][0] = z2; acc[1][1] = z2;

    for (int ac = 0; ac < ATT; ac += 32) {
        __syncthreads();
        {
            const float* up = &u[(size_t)(p0 + urow) * ATT + ac + uas * 8];
            float4 f0 = *(const float4*)up;
            float4 f1 = *(const float4*)(up + 4);
            us[uas*8+0][urow] = f0.x; us[uas*8+1][urow] = f0.y;
            us[uas*8+2][urow] = f0.z; us[uas*8+3][urow] = f0.w;
            us[uas*8+4][urow] = f1.x; us[uas*8+5][urow] = f1.y;
            us[uas*8+6][urow] = f1.z; us[uas*8+7][urow] = f1.w;
            const size_t vidx = (size_t)(n0 + vrow) * ATT + ac + vas * 4;
            float4 g  = *(const float4*)&v1[vidx];
            float4 g2 = *(const float4*)&v2[vidx];
            vs[vas*4+0][vrow] = g.x + g2.x; vs[vas*4+1][vrow] = g.y + g2.y;
            vs[vas*4+2][vrow] = g.z + g2.z; vs[vas*4+3][vrow] = g.w + g2.w;
        }
        __syncthreads();
        #pragma unroll
        for (int a = 0; a < 32; ++a) {
            float4 up4 = *(const float4*)&us[a][tx * 4];
            float2 vn2 = *(const float2*)&vs[a][ty * 2];
            const float w = wfs[ac + a];
            floatx2 u_lo = {up4.x, up4.y}, u_hi = {up4.z, up4.w};
            #pragma unroll
            for (int j = 0; j < 2; ++j) {
                const float vj = j ? vn2.y : vn2.x;
                floatx2 t0 = u_lo + vj;
                floatx2 t1 = u_hi + vj;
                t0.x = fmaxf(t0.x, 0.f); t0.y = fmaxf(t0.y, 0.f);
                t1.x = fmaxf(t1.x, 0.f); t1.y = fmaxf(t1.y, 0.f);
                acc[j][0] = t0 * w + acc[j][0];
                acc[j][1] = t1 * w + acc[j][1];
            }
        }
    }

    #pragma unroll
    for (int j = 0; j < 2; ++j) {
        float4 o;
        o.x = acc[j][0].x; o.y = acc[j][0].y; o.z = acc[j][1].x; o.w = acc[j][1].y;
        *(float4*)&att[(size_t)(n0 + ty * 2 + j) * PP + p0 + tx * 4] = o;
    }
}

// ---------------------------------------------------------------------------
// Row softmax, wave-per-row (no barriers).  Block 256 thr = 4 rows; grid 256.
// ---------------------------------------------------------------------------
__global__ __launch_bounds__(256) void softmax_rows(float* __restrict__ att)
{
    const int wv = threadIdx.x >> 6, lane = threadIdx.x & 63;
    const int n = blockIdx.x * 4 + wv;
    float* row = att + (size_t)n * PP;

    float4 x[4];
    #pragma unroll
    for (int i = 0; i < 4; ++i) x[i] = *(const float4*)&row[i * 256 + lane * 4];

    float m = -1e30f;
    #pragma unroll
    for (int i = 0; i < 4; ++i)
        m = fmaxf(m, fmaxf(fmaxf(x[i].x, x[i].y), fmaxf(x[i].z, x[i].w)));
    #pragma unroll
    for (int off = 32; off > 0; off >>= 1) m = fmaxf(m, __shfl_xor(m, off, 64));

    float s = 0.f;
    #pragma unroll
    for (int i = 0; i < 4; ++i) {
        x[i].x = __expf(x[i].x - m); x[i].y = __expf(x[i].y - m);
        x[i].z = __expf(x[i].z - m); x[i].w = __expf(x[i].w - m);
        s += x[i].x + x[i].y + x[i].z + x[i].w;
    }
    #pragma unroll
    for (int off = 32; off > 0; off >>= 1) s += __shfl_xor(s, off, 64);
    const float inv = 1.0f / s;

    #pragma unroll
    for (int i = 0; i < 4; ++i) {
        x[i].x *= inv; x[i].y *= inv; x[i].z *= inv; x[i].w *= inv;
        *(float4*)&row[i * 256 + lane * 4] = x[i];
    }
}

// ---------------------------------------------------------------------------
extern "C" void kernel_launch(void* const* d_in, const int* in_sizes, int n_in,
                              void* d_out, int out_size, void* d_ws, size_t ws_size,
                              hipStream_t stream)
{
    const float* encoder = (const float*)d_in[0];
    const float* dec     = (const float*)d_in[1];
    const float* lang    = (const float*)d_in[2];
    const float* We      = (const float*)d_in[3];
    const float* be      = (const float*)d_in[4];
    const float* Wt      = (const float*)d_in[5];
    const float* bt      = (const float*)d_in[6];
    const float* Wl      = (const float*)d_in[7];
    const float* bl      = (const float*)d_in[8];
    const float* Wf      = (const float*)d_in[9];
    // d_in[10] = bf: uniform over p -> cancels in softmax.

    float* u  = (float*)d_ws;
    float* v1 = u  + NN * ATT;
    float* v2 = v1 + NN * ATT;

    float* awe   = (float*)d_out;
    float* alpha = (float*)d_out + NN * ENC;

    mfma_uv<<<dim3(ATT / 64, NN / 64, 3), 256, 0, stream>>>(
        encoder, We, be, dec, Wt, bt, lang, Wl, bl, u, v1, v2);
    att_fused<<<dim3(PP / 64, NN / 32), 256, 0, stream>>>(u, v1, v2, Wf, alpha);
    softmax_rows<<<dim3(NN / 4), 256, 0, stream>>>(alpha);
    mfma_awe<<<dim3(ENC / 64, NN / 64), 256, 0, stream>>>(alpha, encoder, awe);
}

// Round 5
// 125.480 us; speedup vs baseline: 1.6878x; 1.1087x over previous
//
#include <hip/hip_runtime.h>
#include <hip/hip_bf16.h>
#include <math.h>

#define ENC 512
#define ATT 256
#define NN 1024
#define PP 1024

typedef __attribute__((ext_vector_type(8))) __bf16 bf16x8;
typedef __attribute__((ext_vector_type(4))) float floatx4;
typedef __attribute__((ext_vector_type(2))) float floatx2;

union LdsVec { uint4 u; bf16x8 v; };

// packed fp32->bf16 RNE via v_cvt_pk_bf16_f32 (gfx950)
__device__ __forceinline__ unsigned cvt_pk(float lo, float hi) {
    union { __hip_bfloat162 h; unsigned u; } x;
    x.h = __float22bfloat162_rn(float2{lo, hi});
    return x.u;
}
__device__ __forceinline__ uint4 cvt8(float4 f0, float4 f1) {
    uint4 r;
    r.x = cvt_pk(f0.x, f0.y); r.y = cvt_pk(f0.z, f0.w);
    r.z = cvt_pk(f1.x, f1.y); r.w = cvt_pk(f1.z, f1.w);
    return r;
}

// LDS tile: [rows][32 k] bf16, row stride 64B; 16B chunks XOR-swizzled.
__device__ __forceinline__ int tile_off(int row, int k) {
    return row * 32 + ((((k >> 3) ^ ((row >> 1) & 3)) & 3) << 3) + (k & 7);
}

// Stage 64-row x 32-k tile of row-major fp32 (ld) into bf16 LDS.
__device__ __forceinline__ void stage_bt(unsigned short* dst, const float* __restrict__ src,
                                         int ld, int k0, int tid) {
    const int row = tid >> 2, kseg = tid & 3;
    const float* p = src + (size_t)row * ld + k0 + kseg * 8;
    float4 f0 = *(const float4*)p;
    float4 f1 = *(const float4*)(p + 4);
    uint4 u = cvt8(f0, f1);
    *(uint4*)&dst[tile_off(row, kseg * 8)] = u;
}

// ---------------------------------------------------------------------------
// Kernel 1 (grid 4 x 16 x 4):
//  z=0: uT  = (E@We^T+be)^T   z=1: v1T = (D@Wt^T+bt)^T  z=2: v2T = (L@Wl^T+bl)^T
//    outputs TRANSPOSED [a=256][m=1024] so att_fused can stage without scatter.
//  z=3: ET = bf16 transpose of encoder (E^T [512][1024]) for mfma_awe.
// GEMM: 64x64 tile, BK=32, 16x16x32 bf16 MFMA, double-buffered LDS.
// ---------------------------------------------------------------------------
__global__ __launch_bounds__(256) void mfma_uv(
    const float* __restrict__ E,  const float* __restrict__ We, const float* __restrict__ be,
    const float* __restrict__ D,  const float* __restrict__ Wt, const float* __restrict__ bt,
    const float* __restrict__ Lg, const float* __restrict__ Wl, const float* __restrict__ bl,
    float* __restrict__ uT, float* __restrict__ v1T, float* __restrict__ v2T,
    unsigned short* __restrict__ ET)
{
    const int tid = threadIdx.x;

    if (blockIdx.z == 3) {
        // ---- E^T bf16 producer: two 64x64 tiles per block ----
        __shared__ unsigned short T[64][72];           // [k][n], stride 72 u16
        const int k0 = blockIdx.y * 64;
        const int kr = tid >> 2, nc = (tid & 3) * 16;  // read coords
        const int nr = tid >> 2, kc = (tid & 3) * 16;  // write coords
        #pragma unroll
        for (int t = 0; t < 2; ++t) {
            const int n0 = (blockIdx.x * 2 + t) * 64;
            const float* ep = E + (size_t)(k0 + kr) * ENC + n0 + nc;
            float4 a = *(const float4*)(ep + 0),  b = *(const float4*)(ep + 4);
            float4 c = *(const float4*)(ep + 8),  d = *(const float4*)(ep + 12);
            if (t) __syncthreads();                    // prior reads done
            *(uint4*)&T[kr][nc]     = cvt8(a, b);
            *(uint4*)&T[kr][nc + 8] = cvt8(c, d);
            __syncthreads();
            unsigned short tmp[16];
            #pragma unroll
            for (int i = 0; i < 16; ++i) tmp[i] = T[kc + i][nr];
            unsigned short* op = ET + (size_t)(n0 + nr) * PP + k0 + kc;
            *(uint4*)(op)     = *(uint4*)&tmp[0];
            *(uint4*)(op + 8) = *(uint4*)&tmp[8];
        }
        return;
    }

    __shared__ __align__(16) unsigned short As[2][64 * 32];
    __shared__ __align__(16) unsigned short Bs[2][64 * 32];
    const int K = 512;

    const float *A, *B, *bias; float* out;
    if      (blockIdx.z == 0) { A = E;  B = We; bias = be; out = uT;  }
    else if (blockIdx.z == 1) { A = D;  B = Wt; bias = bt; out = v1T; }
    else                      { A = Lg; B = Wl; bias = bl; out = v2T; }

    const int m0 = blockIdx.y * 64, n0 = blockIdx.x * 64;
    const int wv = tid >> 6, lm = tid & 15, lq = (tid >> 4) & 3;
    const int mb = (wv & 1) * 32, nb = (wv >> 1) * 32;
    const int a0o = tile_off(mb + lm,      lq * 8);
    const int a1o = tile_off(mb + 16 + lm, lq * 8);
    const int b0o = tile_off(nb + lm,      lq * 8);
    const int b1o = tile_off(nb + 16 + lm, lq * 8);

    const int row = tid >> 2, kseg = tid & 3;
    const int soff = tile_off(row, kseg * 8);
    const float* Ap = A + (size_t)(m0 + row) * K + kseg * 8;
    const float* Bp = B + (size_t)(n0 + row) * K + kseg * 8;

    floatx4 acc[2][2];
    const floatx4 zero = {0.f, 0.f, 0.f, 0.f};
    acc[0][0] = zero; acc[0][1] = zero; acc[1][0] = zero; acc[1][1] = zero;

    float4 pa0 = *(const float4*)(Ap), pa1 = *(const float4*)(Ap + 4);
    float4 pb0 = *(const float4*)(Bp), pb1 = *(const float4*)(Bp + 4);

    for (int k0 = 0; k0 < K; k0 += 32) {
        const int buf = (k0 >> 5) & 1;
        *(uint4*)&As[buf][soff] = cvt8(pa0, pa1);
        *(uint4*)&Bs[buf][soff] = cvt8(pb0, pb1);
        __syncthreads();
        if (k0 + 32 < K) {
            pa0 = *(const float4*)(Ap + k0 + 32); pa1 = *(const float4*)(Ap + k0 + 36);
            pb0 = *(const float4*)(Bp + k0 + 32); pb1 = *(const float4*)(Bp + k0 + 36);
        }
        LdsVec fa0, fa1, fb0, fb1;
        fa0.u = *(const uint4*)&As[buf][a0o];
        fa1.u = *(const uint4*)&As[buf][a1o];
        fb0.u = *(const uint4*)&Bs[buf][b0o];
        fb1.u = *(const uint4*)&Bs[buf][b1o];
        acc[0][0] = __builtin_amdgcn_mfma_f32_16x16x32_bf16(fa0.v, fb0.v, acc[0][0], 0, 0, 0);
        acc[0][1] = __builtin_amdgcn_mfma_f32_16x16x32_bf16(fa0.v, fb1.v, acc[0][1], 0, 0, 0);
        acc[1][0] = __builtin_amdgcn_mfma_f32_16x16x32_bf16(fa1.v, fb0.v, acc[1][0], 0, 0, 0);
        acc[1][1] = __builtin_amdgcn_mfma_f32_16x16x32_bf16(fa1.v, fb1.v, acc[1][1], 0, 0, 0);
    }

    // transposed epilogue: out[a][m], float4 along m (r index)
    #pragma unroll
    for (int s = 0; s < 2; ++s) {
        const int col = n0 + nb + s * 16 + lm;          // a-dim
        const float bsum = bias[col];
        #pragma unroll
        for (int t = 0; t < 2; ++t) {
            const int mbase = m0 + mb + t * 16 + lq * 4;
            float4 o;
            o.x = acc[t][s][0] + bsum; o.y = acc[t][s][1] + bsum;
            o.z = acc[t][s][2] + bsum; o.w = acc[t][s][3] + bsum;
            *(float4*)&out[(size_t)col * NN + mbase] = o;
        }
    }
}

// ---------------------------------------------------------------------------
// Kernel 2: att[n,p] = sum_a relu(uT[a,p] + v1T[a,n] + v2T[a,n]) * Wf[a]
// Tile 64p x 64n, thread 4p x 4n (2 x b128 per 16 out-a -> LDS-optimal).
// z splits a-range in half -> 512 blocks; partials summed in softmax.
// ---------------------------------------------------------------------------
__global__ __launch_bounds__(256) void att_fused(
    const float* __restrict__ uT, const float* __restrict__ v1T,
    const float* __restrict__ v2T,
    const float* __restrict__ Wf, float* __restrict__ att_part)
{
    __shared__ float us[32][68];
    __shared__ float vs[32][68];
    __shared__ float wfs[128];
    const int tid = threadIdx.x;
    const int z = blockIdx.z;
    if (tid < 128) wfs[tid] = Wf[z * 128 + tid];
    const int p0 = blockIdx.x * 64, n0 = blockIdx.y * 64;
    const int rowS = tid >> 3, cS = (tid & 7) * 8;   // staging coords
    const int tx = tid & 15, ty = tid >> 4;          // p = tx*4, n = ty*4

    floatx2 acc[4][2];
    const floatx2 z2 = {0.f, 0.f};
    #pragma unroll
    for (int j = 0; j < 4; ++j) { acc[j][0] = z2; acc[j][1] = z2; }

    const int abase = z * 128;
    for (int ac = 0; ac < 128; ac += 32) {
        __syncthreads();
        {
            const float* up = &uT[(size_t)(abase + ac + rowS) * NN + p0 + cS];
            float4 f0 = *(const float4*)up;
            float4 f1 = *(const float4*)(up + 4);
            *(float4*)&us[rowS][cS]     = f0;
            *(float4*)&us[rowS][cS + 4] = f1;
            const size_t vidx = (size_t)(abase + ac + rowS) * NN + n0 + cS;
            float4 g0 = *(const float4*)&v1T[vidx];
            float4 g1 = *(const float4*)&v1T[vidx + 4];
            float4 h0 = *(const float4*)&v2T[vidx];
            float4 h1 = *(const float4*)&v2T[vidx + 4];
            float4 s0, s1;
            s0.x = g0.x + h0.x; s0.y = g0.y + h0.y; s0.z = g0.z + h0.z; s0.w = g0.w + h0.w;
            s1.x = g1.x + h1.x; s1.y = g1.y + h1.y; s1.z = g1.z + h1.z; s1.w = g1.w + h1.w;
            *(float4*)&vs[rowS][cS]     = s0;
            *(float4*)&vs[rowS][cS + 4] = s1;
        }
        __syncthreads();
        #pragma unroll
        for (int a4 = 0; a4 < 32; a4 += 4) {
            float4 w4 = *(const float4*)&wfs[ac + a4];
            #pragma unroll
            for (int aa = 0; aa < 4; ++aa) {
                const int a = a4 + aa;
                float4 u4 = *(const float4*)&us[a][tx * 4];
                float4 v4 = *(const float4*)&vs[a][ty * 4];
                const float w = (aa == 0) ? w4.x : (aa == 1) ? w4.y : (aa == 2) ? w4.z : w4.w;
                floatx2 ulo = {u4.x, u4.y}, uhi = {u4.z, u4.w};
                const float vv[4] = {v4.x, v4.y, v4.z, v4.w};
                #pragma unroll
                for (int j = 0; j < 4; ++j) {
                    floatx2 t0 = ulo + vv[j];
                    floatx2 t1 = uhi + vv[j];
                    t0 = __builtin_elementwise_max(t0, z2);
                    t1 = __builtin_elementwise_max(t1, z2);
                    acc[j][0] = t0 * w + acc[j][0];
                    acc[j][1] = t1 * w + acc[j][1];
                }
            }
        }
    }

    float* outp = att_part + (size_t)z * NN * PP;
    #pragma unroll
    for (int j = 0; j < 4; ++j) {
        float4 o;
        o.x = acc[j][0].x; o.y = acc[j][0].y; o.z = acc[j][1].x; o.w = acc[j][1].y;
        *(float4*)&outp[(size_t)(n0 + ty * 4 + j) * PP + p0 + tx * 4] = o;
    }
}

// ---------------------------------------------------------------------------
// Kernel 3: softmax over p of (att_part0 + att_part1); writes fp32 alpha to
// d_out AND bf16 alpha to ws for mfma_awe.  Wave-per-row, no barriers.
// ---------------------------------------------------------------------------
__global__ __launch_bounds__(256) void softmax_rows(
    const float* __restrict__ att_part, float* __restrict__ alpha,
    unsigned short* __restrict__ alpha_bf)
{
    const int wv = threadIdx.x >> 6, lane = threadIdx.x & 63;
    const int n = blockIdx.x * 4 + wv;
    const float* r0 = att_part + (size_t)n * PP;
    const float* r1 = att_part + (size_t)NN * PP + (size_t)n * PP;

    float4 x[4];
    #pragma unroll
    for (int i = 0; i < 4; ++i) {
        float4 a = *(const float4*)&r0[i * 256 + lane * 4];
        float4 b = *(const float4*)&r1[i * 256 + lane * 4];
        x[i].x = a.x + b.x; x[i].y = a.y + b.y; x[i].z = a.z + b.z; x[i].w = a.w + b.w;
    }

    float m = -1e30f;
    #pragma unroll
    for (int i = 0; i < 4; ++i)
        m = fmaxf(m, fmaxf(fmaxf(x[i].x, x[i].y), fmaxf(x[i].z, x[i].w)));
    #pragma unroll
    for (int off = 32; off > 0; off >>= 1) m = fmaxf(m, __shfl_xor(m, off, 64));

    float s = 0.f;
    #pragma unroll
    for (int i = 0; i < 4; ++i) {
        x[i].x = __expf(x[i].x - m); x[i].y = __expf(x[i].y - m);
        x[i].z = __expf(x[i].z - m); x[i].w = __expf(x[i].w - m);
        s += x[i].x + x[i].y + x[i].z + x[i].w;
    }
    #pragma unroll
    for (int off = 32; off > 0; off >>= 1) s += __shfl_xor(s, off, 64);
    const float inv = 1.0f / s;

    float* ar = alpha + (size_t)n * PP;
    unsigned short* br = alpha_bf + (size_t)n * PP;
    #pragma unroll
    for (int i = 0; i < 4; ++i) {
        x[i].x *= inv; x[i].y *= inv; x[i].z *= inv; x[i].w *= inv;
        *(float4*)&ar[i * 256 + lane * 4] = x[i];
        uint2 pk;
        pk.x = cvt_pk(x[i].x, x[i].y);
        pk.y = cvt_pk(x[i].z, x[i].w);
        *(uint2*)&br[i * 256 + lane * 4] = pk;
    }
}

// ---------------------------------------------------------------------------
// Kernel 4: awe = alpha @ E, both operands pre-converted bf16 (alpha_bf, ET).
// Tile 32m x 64n, BK=32, 256 blocks, pure copy staging (no cvt / transpose).
// ---------------------------------------------------------------------------
__global__ __launch_bounds__(256) void mfma_awe(
    const unsigned short* __restrict__ alpha_bf,
    const unsigned short* __restrict__ ET, float* __restrict__ awe)
{
    __shared__ __align__(16) unsigned short As[2][32 * 32];
    __shared__ __align__(16) unsigned short Bs[2][64 * 32];
    const int tid = threadIdx.x;
    const int K = PP;
    const int m0 = blockIdx.y * 32, n0 = blockIdx.x * 64;
    const int wv = tid >> 6, lm = tid & 15, lq = (tid >> 4) & 3;
    const int mw = (wv & 1) * 16, nw = (wv >> 1) * 32;
    const int a0o = tile_off(mw + lm,      lq * 8);
    const int b0o = tile_off(nw + lm,      lq * 8);
    const int b1o = tile_off(nw + 16 + lm, lq * 8);

    const int rowA = tid >> 3, kcA = (tid & 7) * 4;   // uint2 per thread
    const int rowB = tid >> 2, kcB = (tid & 3) * 8;   // uint4 per thread
    const int aoff = tile_off(rowA, kcA);
    const int boff = tile_off(rowB, kcB);
    const unsigned short* Ap = alpha_bf + (size_t)(m0 + rowA) * PP + kcA;
    const unsigned short* Bp = ET + (size_t)(n0 + rowB) * PP + kcB;

    floatx4 acc[2];
    const floatx4 zero = {0.f, 0.f, 0.f, 0.f};
    acc[0] = zero; acc[1] = zero;

    uint2 pa = *(const uint2*)Ap;
    uint4 pb = *(const uint4*)Bp;

    for (int k0 = 0; k0 < K; k0 += 32) {
        const int buf = (k0 >> 5) & 1;
        *(uint2*)&As[buf][aoff] = pa;
        *(uint4*)&Bs[buf][boff] = pb;
        __syncthreads();
        if (k0 + 32 < K) {
            pa = *(const uint2*)(Ap + k0 + 32);
            pb = *(const uint4*)(Bp + k0 + 32);
        }
        LdsVec fa, fb0, fb1;
        fa.u  = *(const uint4*)&As[buf][a0o];
        fb0.u = *(const uint4*)&Bs[buf][b0o];
        fb1.u = *(const uint4*)&Bs[buf][b1o];
        acc[0] = __builtin_amdgcn_mfma_f32_16x16x32_bf16(fa.v, fb0.v, acc[0], 0, 0, 0);
        acc[1] = __builtin_amdgcn_mfma_f32_16x16x32_bf16(fa.v, fb1.v, acc[1], 0, 0, 0);
    }

    #pragma unroll
    for (int s = 0; s < 2; ++s) {
        const int col = n0 + nw + s * 16 + lm;
        #pragma unroll
        for (int r = 0; r < 4; ++r)
            awe[(size_t)(m0 + mw + lq * 4 + r) * ENC + col] = acc[s][r];
    }
}

// ---------------------------------------------------------------------------
extern "C" void kernel_launch(void* const* d_in, const int* in_sizes, int n_in,
                              void* d_out, int out_size, void* d_ws, size_t ws_size,
                              hipStream_t stream)
{
    const float* encoder = (const float*)d_in[0];
    const float* dec     = (const float*)d_in[1];
    const float* lang    = (const float*)d_in[2];
    const float* We      = (const float*)d_in[3];
    const float* be      = (const float*)d_in[4];
    const float* Wt      = (const float*)d_in[5];
    const float* bt      = (const float*)d_in[6];
    const float* Wl      = (const float*)d_in[7];
    const float* bl      = (const float*)d_in[8];
    const float* Wf      = (const float*)d_in[9];
    // d_in[10] = bf: uniform over p -> cancels in softmax.

    float* uT   = (float*)d_ws;                  // [256][1024]
    float* v1T  = uT  + ATT * NN;                // [256][1024]
    float* v2T  = v1T + ATT * NN;                // [256][1024]
    float* attp = v2T + ATT * NN;                // [2][1024][1024]
    unsigned short* alpha_bf = (unsigned short*)(attp + 2 * (size_t)NN * PP);  // [1024][1024]
    unsigned short* ET       = alpha_bf + (size_t)NN * PP;                     // [512][1024]

    float* awe   = (float*)d_out;                // (1024, 512)
    float* alpha = (float*)d_out + NN * ENC;     // (1024, 1024)

    mfma_uv<<<dim3(4, 16, 4), 256, 0, stream>>>(
        encoder, We, be, dec, Wt, bt, lang, Wl, bl, uT, v1T, v2T, ET);
    att_fused<<<dim3(PP / 64, NN / 64, 2), 256, 0, stream>>>(uT, v1T, v2T, Wf, attp);
    softmax_rows<<<dim3(NN / 4), 256, 0, stream>>>(attp, alpha, alpha_bf);
    mfma_awe<<<dim3(ENC / 64, NN / 32), 256, 0, stream>>>(alpha_bf, ET, awe);
}